// Round 5
// baseline (131.770 us; speedup 1.0000x reference)
//
#include <hip/hip_runtime.h>

typedef float f4 __attribute__((ext_vector_type(4)));

#define PAD 68   // 64x64 LDS matrix row stride: 68*4=272 B (16B-aligned), banks (4i+j)%32

// Chebyshev deg-2 minimax seed for 1/lambda on [2.55, 4.40]:
// X0 = C2*M^2 + C1*M + C0*I ; residual rho = 1/T3(3.7568) = 4.98e-3
#define SEED_C2 0.0251681f
#define SEED_C1 (-0.262380f)
#define SEED_C0 0.895613f

// acc[m*4+c] = sum_n L[i0+m][n] * R[n][j0+c]   (row stride PAD)
__device__ __forceinline__ void mm_acc(const float* L, const float* R,
                                       int i0, int j0, float acc[16]) {
  #pragma unroll
  for (int m = 0; m < 16; ++m) acc[m] = 0.f;
  #pragma unroll
  for (int n = 0; n < 64; n += 4) {
    f4 La[4], Rb[4];
    #pragma unroll
    for (int m = 0; m < 4; ++m) La[m] = *(const f4*)&L[(i0 + m) * PAD + n];
    #pragma unroll
    for (int p = 0; p < 4; ++p) Rb[p] = *(const f4*)&R[(n + p) * PAD + j0];
    #pragma unroll
    for (int m = 0; m < 4; ++m)
      #pragma unroll
      for (int p = 0; p < 4; ++p)
        #pragma unroll
        for (int c = 0; c < 4; ++c)
          acc[m * 4 + c] += La[m][p] * Rb[p][c];
  }
}

__device__ __forceinline__ void store_tile(float* Dst, int i0, int j0, const float acc[16]) {
  #pragma unroll
  for (int m = 0; m < 4; ++m) {
    f4 t = {acc[m*4+0], acc[m*4+1], acc[m*4+2], acc[m*4+3]};
    *(f4*)&Dst[(i0 + m) * PAD + j0] = t;
  }
}

// One block per channel d. K[k] = Cv . A_bar^k . B_bar, k=0..63 (k=4i+j).
// Inverse via Chebyshev seed + 1 Newton; chains batched via A^2, A^4, A^16.
// Writes K TRANSPOSED: Kout[k*128 + d].
__global__ __launch_bounds__(256) void s4_discretize(
    const float* __restrict__ Ag,   // (128,64,64)
    const float* __restrict__ Bg,   // (128,64)
    const float* __restrict__ Cg,   // (128,64)
    float* __restrict__ Kout)       // (64,128)
{
  __shared__ float Ms[64 * PAD];    // M -> A_bar
  __shared__ float Xs[64 * PAD];    // X0 -> M^-1 -> A^4
  __shared__ float Ts[64 * PAD];    // M^2 -> MX0 -> A^2
  __shared__ float Qs[64 * PAD];    // A^16
  __shared__ float C4[4][PAD];      // Cv . A_bar^j
  __shared__ float U16[16][PAD];    // (A^4)^i . B_bar  (row-major: bank-friendly)
  __shared__ float Bv[64], Cv0[64], Bb[64];
  __shared__ float Pr[4][64];

  const int d   = blockIdx.x;
  const int tid = threadIdx.x;
  const int i0  = (tid >> 4) << 2;
  const int j0  = (tid & 15) << 2;
  const int q   = tid >> 6;
  const int ln  = tid & 63;

  // ---- load A (f4), build M = I - 0.05A ----
  {
    const f4* Af = (const f4*)(Ag + (size_t)d * 4096);
    #pragma unroll
    for (int s = 0; s < 4; ++s) {
      int idx4 = tid + s * 256;               // 1024 f4 total
      int i = idx4 >> 4, jb = (idx4 & 15) << 2;
      f4 a = Af[idx4];
      f4 m;
      #pragma unroll
      for (int c = 0; c < 4; ++c)
        m[c] = ((i == jb + c) ? 1.f : 0.f) - 0.05f * a[c];
      *(f4*)&Ms[i * PAD + jb] = m;
    }
  }
  if (tid < 64) { Bv[tid] = Bg[d * 64 + tid]; Cv0[tid] = Cg[d * 64 + tid]; }
  __syncthreads();

  float acc[16];

  // ---- Ts = M^2 ----
  mm_acc(Ms, Ms, i0, j0, acc);
  store_tile(Ts, i0, j0, acc);
  __syncthreads();

  // ---- Xs = seed X0 = C2*M^2 + C1*M + C0*I ----
  for (int idx = tid; idx < 4096; idx += 256) {
    int i = idx >> 6, j = idx & 63;
    float v = SEED_C2 * Ts[i * PAD + j] + SEED_C1 * Ms[i * PAD + j]
            + ((i == j) ? SEED_C0 : 0.f);
    Xs[i * PAD + j] = v;
  }
  __syncthreads();

  // ---- one Newton step: X <- 2X - X(MX)  (residual ~2.5e-5) ----
  mm_acc(Ms, Xs, i0, j0, acc);     // T = M X0   (M^2 dead)
  store_tile(Ts, i0, j0, acc);
  __syncthreads();
  mm_acc(Xs, Ts, i0, j0, acc);     // X0 T
  __syncthreads();                 // all reads of X0 done
  #pragma unroll
  for (int m = 0; m < 4; ++m) {
    f4 xo = *(const f4*)&Xs[(i0 + m) * PAD + j0];
    f4 t = {acc[m*4+0], acc[m*4+1], acc[m*4+2], acc[m*4+3]};
    *(f4*)&Xs[(i0 + m) * PAD + j0] = 2.f * xo - t;
  }
  __syncthreads();
  // Xs = M^-1

  // ---- B_bar partials; A_bar = 2X - I -> Ms; C4[0] = Cv ----
  {
    float p = 0.f;
    #pragma unroll
    for (int m = 0; m < 16; ++m) p += Xs[ln * PAD + q * 16 + m] * Bv[q * 16 + m];
    Pr[q][ln] = p;
  }
  for (int idx = tid; idx < 4096; idx += 256) {
    int i = idx >> 6, j = idx & 63;
    Ms[i * PAD + j] = 2.f * Xs[i * PAD + j] - ((i == j) ? 1.f : 0.f);
  }
  if (tid < 64) C4[0][tid] = Cv0[tid];
  __syncthreads();

  // ---- Bb = 0.1 * M^-1 B ; Ts = A^2 ----
  if (tid < 64) Bb[tid] = 0.1f * (Pr[0][tid] + Pr[1][tid] + Pr[2][tid] + Pr[3][tid]);
  mm_acc(Ms, Ms, i0, j0, acc);
  store_tile(Ts, i0, j0, acc);
  __syncthreads();

  // ---- Xs = A^4 (M^-1 dead); U16[0] = Bb ----
  mm_acc(Ts, Ts, i0, j0, acc);
  __syncthreads();
  store_tile(Xs, i0, j0, acc);
  if (tid < 64) U16[0][tid] = Bb[tid];
  __syncthreads();

  // ---- Qs = A^16 ----
  mm_acc(Xs, Xs, i0, j0, acc);
  store_tile(Qs, i0, j0, acc);
  // (no dependence of next round on Qs yet; barrier below covers it)

  // ---- C chain round 1: c1 = c0 . A_bar (column reads, 2-way banks) ----
  __syncthreads();
  if (tid < 64) {
    float s = 0.f;
    #pragma unroll
    for (int m = 0; m < 64; ++m) s += C4[0][m] * Ms[m * PAD + tid];
    C4[1][tid] = s;
  }
  __syncthreads();

  // ---- C chain round 2 (batched): c2 = c0.A^2, c3 = c1.A^2 ----
  if (tid < 128) {
    int j = 2 + (tid >> 6), n = tid & 63;
    float s = 0.f;
    #pragma unroll
    for (int m = 0; m < 64; ++m) s += C4[j - 2][m] * Ts[m * PAD + n];
    C4[j][n] = s;
  }
  __syncthreads();

  // ---- U chain: u1..u3 = A^4 . u_{i-1} (f4 row reads + broadcast) ----
  for (int i = 1; i < 4; ++i) {
    if (tid < 64) {
      f4 s = {0.f, 0.f, 0.f, 0.f};
      const f4* Arow = (const f4*)&Xs[tid * PAD];
      const f4* uv   = (const f4*)&U16[i - 1][0];
      #pragma unroll
      for (int m = 0; m < 16; ++m) s += Arow[m] * uv[m];
      U16[i][tid] = s[0] + s[1] + s[2] + s[3];
    }
    __syncthreads();
  }

  // ---- U chain batched: [u_{b+4}..u_{b+7}] = A^16 . [u_b..u_{b+3}] ----
  #pragma unroll
  for (int base = 0; base < 12; base += 4) {
    int v = tid >> 6, n = tid & 63;
    f4 s = {0.f, 0.f, 0.f, 0.f};
    const f4* Arow = (const f4*)&Qs[n * PAD];
    const f4* uv   = (const f4*)&U16[base + v][0];
    #pragma unroll
    for (int m = 0; m < 16; ++m) s += Arow[m] * uv[m];
    __syncthreads();                       // reads done before writes (base+4 may alias next read)
    U16[base + 4 + v][n] = s[0] + s[1] + s[2] + s[3];
    __syncthreads();
  }

  // ---- K[k] = c_{k&3} . u_{k>>2}, write transposed ----
  if (tid < 64) {
    int i = tid >> 2, j = tid & 3;
    f4 s = {0.f, 0.f, 0.f, 0.f};
    const f4* cj = (const f4*)&C4[j][0];
    const f4* ui = (const f4*)&U16[i][0];
    #pragma unroll
    for (int n = 0; n < 16; ++n) s += cj[n] * ui[n];
    Kout[tid * 128 + d] = s[0] + s[1] + s[2] + s[3];
  }
}

// Depthwise causal conv, 64 taps. Block: 32 d x 256 t tile; thread = (dl, g) does 32 t.
__global__ __launch_bounds__(256) void s4_conv(
    const float* __restrict__ xg,   // (16,4096,128)
    const float* __restrict__ Ktg,  // (64,128) transposed K
    float* __restrict__ yg)         // (16,4096,128)
{
  __shared__ float xs[319 * 32];    // 40,832 B
  __shared__ float Ks[64 * 32];     //  8,192 B

  const int tid = threadIdx.y * 32 + threadIdx.x;
  const int tc  = blockIdx.x;
  const int dq  = blockIdx.y;
  const int b   = blockIdx.z;
  const int d0  = dq * 32;
  const int t0  = tc * 256;

  for (int idx = tid; idx < 2048; idx += 256)
    Ks[idx] = Ktg[(idx >> 5) * 128 + d0 + (idx & 31)];

  const float* xb = xg + (size_t)b * 4096 * 128 + d0;
  for (int idx = tid; idx < 319 * 8; idx += 256) {
    int row = idx >> 3, c4 = (idx & 7) << 2;
    int t = t0 - 63 + row;
    f4 v = {0.f, 0.f, 0.f, 0.f};
    if (t >= 0) v = *(const f4*)&xb[(size_t)t * 128 + c4];
    *(f4*)&xs[row * 32 + c4] = v;
  }
  __syncthreads();

  const int dl = threadIdx.x;
  const int g  = threadIdx.y;

  float acc[32];
  #pragma unroll
  for (int t = 0; t < 32; ++t) acc[t] = 0.f;

  float w[47];
  #pragma unroll
  for (int k0 = 0; k0 < 64; k0 += 16) {
    const int base = g * 32 + 48 - k0;
    #pragma unroll
    for (int jj = 0; jj < 47; ++jj) w[jj] = xs[(base + jj) * 32 + dl];
    #pragma unroll
    for (int k = k0; k < k0 + 16; ++k) {
      float kv = Ks[k * 32 + dl];
      #pragma unroll
      for (int t = 0; t < 32; ++t)
        acc[t] += kv * w[t + (k0 + 15 - k)];
    }
  }

  float* yb = yg + ((size_t)b * 4096 + t0 + g * 32) * 128 + d0 + dl;
  #pragma unroll
  for (int t = 0; t < 32; ++t)
    yb[(size_t)t * 128] = acc[t];
}

extern "C" void kernel_launch(void* const* d_in, const int* in_sizes, int n_in,
                              void* d_out, int out_size, void* d_ws, size_t ws_size,
                              hipStream_t stream) {
  const float* x = (const float*)d_in[0];
  const float* A = (const float*)d_in[1];
  const float* B = (const float*)d_in[2];
  const float* C = (const float*)d_in[3];
  float* y  = (float*)d_out;
  float* Kt = (float*)d_ws;   // 64*128*4 = 32 KB scratch

  s4_discretize<<<128, 256, 0, stream>>>(A, B, C, Kt);
  dim3 grid(16, 4, 16), block(32, 8);
  s4_conv<<<grid, block, 0, stream>>>(x, Kt, y);
}

// Round 6
// 122.265 us; speedup vs baseline: 1.0777x; 1.0777x over previous
//
#include <hip/hip_runtime.h>

typedef float f4 __attribute__((ext_vector_type(4)));

#define PAD 68   // 64x64 LDS matrix row stride: 272 B, 16B-aligned

// Chebyshev deg-2 minimax seed for 1/lambda on [2.55, 4.40]:
// X0 = C2*M^2 + C1*M + C0*I ; residual ~5.0e-3, after 1 Newton ~2.5e-5
#define SEED_C2 0.0251681f
#define SEED_C1 (-0.262380f)
#define SEED_C0 0.895613f

// acc[m*4+c] = sum_n L[i0+m][n] * R[n][j0+c]   (row stride PAD)
__device__ __forceinline__ void mm_acc(const float* L, const float* R,
                                       int i0, int j0, float acc[16]) {
  #pragma unroll
  for (int m = 0; m < 16; ++m) acc[m] = 0.f;
  #pragma unroll
  for (int n = 0; n < 64; n += 4) {
    f4 La[4], Rb[4];
    #pragma unroll
    for (int m = 0; m < 4; ++m) La[m] = *(const f4*)&L[(i0 + m) * PAD + n];
    #pragma unroll
    for (int p = 0; p < 4; ++p) Rb[p] = *(const f4*)&R[(n + p) * PAD + j0];
    #pragma unroll
    for (int m = 0; m < 4; ++m)
      #pragma unroll
      for (int p = 0; p < 4; ++p)
        #pragma unroll
        for (int c = 0; c < 4; ++c)
          acc[m * 4 + c] += La[m][p] * Rb[p][c];
  }
}

__device__ __forceinline__ void store_tile(float* Dst, int i0, int j0, const float acc[16]) {
  #pragma unroll
  for (int m = 0; m < 4; ++m) {
    f4 t = {acc[m*4+0], acc[m*4+1], acc[m*4+2], acc[m*4+3]};
    *(f4*)&Dst[(i0 + m) * PAD + j0] = t;
  }
}

// One block per channel d. K[k] = Cv . A_bar^k . B_bar via Cheb-seeded Newton
// inverse + power doubling. Writes K TRANSPOSED: Kout[k*128 + d].
__global__ __launch_bounds__(256) void s4_discretize(
    const float* __restrict__ Ag,   // (128,64,64)
    const float* __restrict__ Bg,   // (128,64)
    const float* __restrict__ Cg,   // (128,64)
    float* __restrict__ Kout)       // (64,128)
{
  __shared__ float Ms[64 * PAD];    // M, later A_bar
  __shared__ float Xs[64 * PAD];    // seed -> M^-1, later A_bar^4
  __shared__ float Ts[64 * PAD];    // M^2 -> MX temp -> A_bar^2
  __shared__ float C4[4][65];       // Cv . A_bar^j
  __shared__ float U16[64][16];     // A4^i . B_bar
  __shared__ float Bv[64], Cv0[64], Bb[64];
  __shared__ float Pr[4][64];

  const int d   = blockIdx.x;
  const int tid = threadIdx.x;
  const int i0  = (tid >> 4) << 2;  // output row tile
  const int j0  = (tid & 15) << 2;  // output col tile
  const int q   = tid >> 6;         // wave id 0..3
  const int ln  = tid & 63;

  // ---- load, build M = I - 0.05A ----
  for (int idx = tid; idx < 4096; idx += 256) {
    int i = idx >> 6, j = idx & 63;
    float a = Ag[(size_t)d * 4096 + idx];
    Ms[i * PAD + j] = ((i == j) ? 1.f : 0.f) - 0.05f * a;
  }
  if (tid < 64) { Bv[tid] = Bg[d * 64 + tid]; Cv0[tid] = Cg[d * 64 + tid]; }
  __syncthreads();

  float acc[16];

  // ---- Ts = M^2 ----
  mm_acc(Ms, Ms, i0, j0, acc);
  store_tile(Ts, i0, j0, acc);
  __syncthreads();

  // ---- Xs = seed X0 = C2*M^2 + C1*M + C0*I ----
  for (int idx = tid; idx < 4096; idx += 256) {
    int i = idx >> 6, j = idx & 63;
    Xs[i * PAD + j] = SEED_C2 * Ts[i * PAD + j] + SEED_C1 * Ms[i * PAD + j]
                    + ((i == j) ? SEED_C0 : 0.f);
  }
  __syncthreads();

  // ---- one Newton step: X <- 2X - X(MX) ----
  mm_acc(Ms, Xs, i0, j0, acc);                // T = M X0 (M^2 dead)
  store_tile(Ts, i0, j0, acc);
  __syncthreads();
  mm_acc(Xs, Ts, i0, j0, acc);                // X0 T
  __syncthreads();                            // all reads of X0 done
  #pragma unroll
  for (int m = 0; m < 4; ++m) {
    f4 xo = *(const f4*)&Xs[(i0 + m) * PAD + j0];
    f4 t = {acc[m*4+0], acc[m*4+1], acc[m*4+2], acc[m*4+3]};
    *(f4*)&Xs[(i0 + m) * PAD + j0] = 2.f * xo - t;
  }
  __syncthreads();
  // Xs = M^-1 (resid ~2.5e-5)

  // ---- B_bar = 0.1 * X Bv ; A_bar = 2X - I -> Ms ----
  {
    float p = 0.f;
    #pragma unroll
    for (int m = 0; m < 16; ++m) p += Xs[ln * PAD + q * 16 + m] * Bv[q * 16 + m];
    Pr[q][ln] = p;
  }
  for (int idx = tid; idx < 4096; idx += 256) {
    int i = idx >> 6, j = idx & 63;
    Ms[i * PAD + j] = 2.f * Xs[i * PAD + j] - ((i == j) ? 1.f : 0.f);
  }
  __syncthreads();
  if (tid < 64) Bb[tid] = 0.1f * (Pr[0][tid] + Pr[1][tid] + Pr[2][tid] + Pr[3][tid]);
  __syncthreads();

  // ---- C chain: c_j = Cv . A_bar^j, j=0..3 ----
  if (tid < 64) C4[0][tid] = Cv0[tid];
  __syncthreads();
  for (int j = 1; j < 4; ++j) {
    float p = 0.f;
    #pragma unroll
    for (int m = 0; m < 16; ++m) p += C4[j - 1][q * 16 + m] * Ms[(q * 16 + m) * PAD + ln];
    Pr[q][ln] = p;
    __syncthreads();
    if (q == 0) C4[j][ln] = Pr[0][ln] + Pr[1][ln] + Pr[2][ln] + Pr[3][ln];
    __syncthreads();
  }

  // ---- A^2 -> Ts ; A^4 -> Xs ----
  mm_acc(Ms, Ms, i0, j0, acc);
  #pragma unroll
  for (int m = 0; m < 4; ++m) {
    f4 t = {acc[m*4+0], acc[m*4+1], acc[m*4+2], acc[m*4+3]};
    *(f4*)&Ts[(i0 + m) * PAD + j0] = t;
  }
  __syncthreads();
  mm_acc(Ts, Ts, i0, j0, acc);
  __syncthreads();
  #pragma unroll
  for (int m = 0; m < 4; ++m) {
    f4 t = {acc[m*4+0], acc[m*4+1], acc[m*4+2], acc[m*4+3]};
    *(f4*)&Xs[(i0 + m) * PAD + j0] = t;
  }
  __syncthreads();

  // ---- U chain: u_i = A4^i . B_bar, i=0..15 ----
  if (tid < 64) U16[tid][0] = Bb[tid];
  __syncthreads();
  for (int i = 1; i < 16; ++i) {
    float p = 0.f;
    #pragma unroll
    for (int m = 0; m < 16; ++m) p += Xs[ln * PAD + q * 16 + m] * U16[q * 16 + m][i - 1];
    Pr[q][ln] = p;
    __syncthreads();
    if (q == 0) U16[ln][i] = Pr[0][ln] + Pr[1][ln] + Pr[2][ln] + Pr[3][ln];
    __syncthreads();
  }

  // ---- K[k] = c_{k&3} . u_{k>>2}, write transposed ----
  if (tid < 64) {
    int i = tid >> 2, j = tid & 3;
    float s = 0.f;
    #pragma unroll
    for (int n = 0; n < 64; ++n) s += C4[j][n] * U16[n][i];
    Kout[tid * 128 + d] = s;
  }
}

// Depthwise causal conv, 64 taps. Block: 32 d x 256 t tile; thread = (dl, g) does 32 t.
// LDS 49 KB -> 3 blocks/CU (12 waves); halo ratio 319/256 = 1.25x.
__global__ __launch_bounds__(256) void s4_conv(
    const float* __restrict__ xg,   // (16,4096,128)
    const float* __restrict__ Ktg,  // (64,128) transposed K
    float* __restrict__ yg)         // (16,4096,128)
{
  __shared__ float xs[319 * 32];    // 40,832 B
  __shared__ float Ks[64 * 32];     //  8,192 B

  const int tid = threadIdx.y * 32 + threadIdx.x;
  const int tc  = blockIdx.x;
  const int dq  = blockIdx.y;
  const int b   = blockIdx.z;
  const int d0  = dq * 32;
  const int t0  = tc * 256;

  for (int idx = tid; idx < 2048; idx += 256)
    Ks[idx] = Ktg[(idx >> 5) * 128 + d0 + (idx & 31)];

  const float* xb = xg + (size_t)b * 4096 * 128 + d0;
  for (int idx = tid; idx < 319 * 8; idx += 256) {
    int row = idx >> 3, c4 = (idx & 7) << 2;
    int t = t0 - 63 + row;
    f4 v = {0.f, 0.f, 0.f, 0.f};
    if (t >= 0) v = *(const f4*)&xb[(size_t)t * 128 + c4];
    *(f4*)&xs[row * 32 + c4] = v;
  }
  __syncthreads();

  const int dl = threadIdx.x;
  const int g  = threadIdx.y;

  float acc[32];
  #pragma unroll
  for (int t = 0; t < 32; ++t) acc[t] = 0.f;

  float w[47];
  #pragma unroll
  for (int k0 = 0; k0 < 64; k0 += 16) {
    const int base = g * 32 + 48 - k0;
    #pragma unroll
    for (int jj = 0; jj < 47; ++jj) w[jj] = xs[(base + jj) * 32 + dl];
    #pragma unroll
    for (int k = k0; k < k0 + 16; ++k) {
      float kv = Ks[k * 32 + dl];
      #pragma unroll
      for (int t = 0; t < 32; ++t)
        acc[t] += kv * w[t + (k0 + 15 - k)];
    }
  }

  float* yb = yg + ((size_t)b * 4096 + t0 + g * 32) * 128 + d0 + dl;
  #pragma unroll
  for (int t = 0; t < 32; ++t)
    yb[(size_t)t * 128] = acc[t];
}

extern "C" void kernel_launch(void* const* d_in, const int* in_sizes, int n_in,
                              void* d_out, int out_size, void* d_ws, size_t ws_size,
                              hipStream_t stream) {
  const float* x = (const float*)d_in[0];
  const float* A = (const float*)d_in[1];
  const float* B = (const float*)d_in[2];
  const float* C = (const float*)d_in[3];
  float* y  = (float*)d_out;
  float* Kt = (float*)d_ws;   // 64*128*4 = 32 KB scratch

  s4_discretize<<<128, 256, 0, stream>>>(A, B, C, Kt);
  dim3 grid(16, 4, 16), block(32, 8);
  s4_conv<<<grid, block, 0, stream>>>(x, Kt, y);
}